// Round 1
// baseline (302.229 us; speedup 1.0000x reference)
//
#include <hip/hip_runtime.h>
#include <stdint.h>

#define NROW 256
#define NV   128000
#define NV4  (NV / 4)
#define NT   1024
#define NBIN 7680
#define NCH  8            // bins per thread in the suffix scan (covers 8192 >= NBIN)
#define BLO  0x42300000u  // bits of 44.0f
#define BSH  10           // bin = (bits(t) - BLO) >> 10 ; t = clamp(s+64, 44, 84)
#define GCAP 4096         // gather capacity (power of 2 for bitonic sort)

__global__ __launch_bounds__(NT, 1)
void sampler_kernel(const float* __restrict__ logits,
                    const float* __restrict__ temps,
                    const float* __restrict__ topps,
                    const float* __restrict__ unoise,
                    int* __restrict__ out)
{
    __shared__ float qmass[NBIN];          // 30.7 KB : per-bin mass in exp(s)*2^-20 units
    __shared__ float ct[NT];               // 4 KB    : chunk totals / scan ping
    __shared__ float ct2[NT];              // 4 KB    : scan pong
    __shared__ unsigned long long gkeys[GCAP]; // 32 KB: gathered (pbits<<32)|(~idx)
    __shared__ float sa[GCAP];             // 16 KB   : prefix-scan ping
    __shared__ float sb[GCAP];             // 16 KB   : prefix-scan pong
    __shared__ float wred[16];
    __shared__ unsigned long long sh_cross;
    __shared__ unsigned long long sh_best;
    __shared__ unsigned int gcnt;
    __shared__ int sh_bstar;
    __shared__ float sh_A;                 // q-units mass of bins >= bstar+2
    __shared__ float sh_m;
    __shared__ float sh_Zq;
    __shared__ int sh_kstar;

    const int row = blockIdx.x;
    const int tid = threadIdx.x;
    const float* __restrict__ lrow = logits + (size_t)row * NV;
    const float* __restrict__ urow = unoise + (size_t)row * NV;
    const float invT = 1.0f / temps[row];
    const float topp = topps[row];

    for (int b = tid; b < NBIN; b += NT) qmass[b] = 0.0f;
    if (tid == 0) {
        sh_cross = 0ull; sh_best = 0ull; gcnt = 0u; sh_kstar = 0;
        sh_bstar = 0; sh_A = 0.0f;
    }
    __syncthreads();

    // ---------------- Pass 1: row max + q-space histogram (reads logits) ----
    const float4* __restrict__ l4 = (const float4*)lrow;
    float mloc = -3.402823466e38f;
    const float qscale = 9.5367431640625e-07f; // 2^-20 (overflow headroom)
    for (int v = tid; v < NV4; v += NT) {
        float4 x = l4[v];
        float xs[4] = {x.x, x.y, x.z, x.w};
        #pragma unroll
        for (int c = 0; c < 4; ++c) {
            float s = xs[c] * invT;
            mloc = fmaxf(mloc, s);
            float q = __expf(s) * qscale;
            float t = fminf(fmaxf(s + 64.0f, 44.0f), 84.0f);
            int bin = (int)((__float_as_uint(t) - BLO) >> BSH);
            bin = min(bin, NBIN - 1);
            atomicAdd(&qmass[bin], q);
        }
    }
    // block max reduction
    #pragma unroll
    for (int o = 32; o > 0; o >>= 1) mloc = fmaxf(mloc, __shfl_down(mloc, o, 64));
    if ((tid & 63) == 0) wred[tid >> 6] = mloc;
    __syncthreads();
    if (tid < 16) {
        float vv = wred[tid];
        #pragma unroll
        for (int o = 8; o > 0; o >>= 1) vv = fmaxf(vv, __shfl_down(vv, o, 16));
        if (tid == 0) sh_m = vv;
    }
    __syncthreads();
    const float m = sh_m;

    // ---------------- suffix scan over bins -> crossing bin b* --------------
    const int b0 = tid * NCH;
    float chs = 0.0f;
    #pragma unroll
    for (int i2 = 0; i2 < NCH; ++i2) {
        int b = b0 + i2;
        if (b < NBIN) chs += qmass[b];
    }
    ct[tid] = chs;
    __syncthreads();
    float* src = ct; float* dst = ct2;
    for (int d = 1; d < NT; d <<= 1) {           // suffix-inclusive Hillis-Steele
        float val = src[tid] + ((tid + d < NT) ? src[tid + d] : 0.0f);
        dst[tid] = val;
        __syncthreads();
        float* tm = src; src = dst; dst = tm;
    }
    const float Zq = src[0];
    const float P = topp * Zq;
    {   // stage A: crossing chunk = largest t with suffix[t] > P >= suffix[t+1]
        float mine = src[tid];
        float nxt = (tid + 1 < NT) ? src[tid + 1] : 0.0f;
        if (mine > P && nxt <= P)
            atomicMax(&sh_cross, ((unsigned long long)(tid + 1) << 32));
    }
    __syncthreads();
    if (tid == 0) {
        sh_Zq = Zq;
        if (sh_cross == 0ull) {
            sh_bstar = -1000000;   // top_p >= total mass: keep everything
            sh_A = 0.0f;
        } else {
            int cstar = (int)(sh_cross >> 32) - 1;
            float run = (cstar + 1 < NT) ? src[cstar + 1] : 0.0f;
            int bst = -1; float abv = run;
            for (int i2 = NCH - 1; i2 >= 0; --i2) {   // stage B: within chunk
                int b = cstar * NCH + i2;
                if (b >= NBIN) continue;
                float inc = qmass[b];
                if (run <= P && run + inc > P) { bst = b; abv = run; break; }
                run += inc;
            }
            if (bst < 0) { bst = cstar * NCH; abv = run; }   // defensive
            sh_bstar = bst;
            float A = abv;                          // mass of bins > bst
            if (bst + 1 < NBIN) A -= qmass[bst + 1]; // -> mass of bins >= bst+2
            if (A < 0.0f) A = 0.0f;
            sh_A = A;
        }
    }
    __syncthreads();

    const int bstar = sh_bstar;
    const float Zrow = sh_Zq * 1048576.0f * __expf(-m);  // ~ sum exp(s - m)
    const float invZrow = 1.0f / Zrow;

    // -------- Pass 2: argmax over definitely-kept + gather boundary bins ----
    // reads logits (again; mostly L3) + u_noise
    const float4* __restrict__ u4 = (const float4*)urow;
    unsigned long long mybest = 0ull;
    for (int v = tid; v < NV4; v += NT) {
        float4 x = l4[v];
        float4 uu = u4[v];
        float xs[4] = {x.x, x.y, x.z, x.w};
        float us[4] = {uu.x, uu.y, uu.z, uu.w};
        #pragma unroll
        for (int c = 0; c < 4; ++c) {
            float s = xs[c] * invT;
            float t = fminf(fmaxf(s + 64.0f, 44.0f), 84.0f);
            int bin = (int)((__float_as_uint(t) - BLO) >> BSH);
            bin = min(bin, NBIN - 1);
            if (bin >= bstar + 2) {
                // definitely inside the nucleus: race entry r = p / e_noise
                float e = __expf(s - m);
                float noise = fmaxf(-__logf(us[c]), 1e-10f);
                float r = __fdividef(e * invZrow, noise);
                int i = v * 4 + c;
                unsigned long long key = ((unsigned long long)__float_as_uint(r) << 32)
                                       | (unsigned long long)(0xFFFFFFFFu - (unsigned)i);
                if (key > mybest) mybest = key;
            } else if (bin >= bstar - 1) {
                // boundary region: exact p for tie-faithful sort
                float e = __expf(s - m);
                float p = e / Zrow;
                int i = v * 4 + c;
                unsigned int pos = atomicAdd(&gcnt, 1u);
                if (pos < GCAP)
                    gkeys[pos] = ((unsigned long long)__float_as_uint(p) << 32)
                               | (unsigned long long)(0xFFFFFFFFu - (unsigned)i);
            }
        }
    }
    atomicMax(&sh_best, mybest);
    __syncthreads();

    // -------- Pass 3 (LDS only): sort boundary, find exact cut, argmax ------
    unsigned int ngu = gcnt; if (ngu > GCAP) ngu = GCAP;
    const int ng = (int)ngu;
    for (int i = tid; i < GCAP; i += NT) if (i >= ng) gkeys[i] = 0ull;
    __syncthreads();
    if (ng > 0) {
        // bitonic sort descending on (pbits, ~idx): p desc, idx asc (stable tie order)
        for (int k = 2; k <= GCAP; k <<= 1) {
            for (int j = k >> 1; j > 0; j >>= 1) {
                for (int i = tid; i < GCAP; i += NT) {
                    int ixj = i ^ j;
                    if (ixj > i) {
                        unsigned long long a = gkeys[i], b = gkeys[ixj];
                        bool up = ((i & k) == 0);
                        bool sw = up ? (a < b) : (a > b);
                        if (sw) { gkeys[i] = b; gkeys[ixj] = a; }
                    }
                }
                __syncthreads();
            }
        }
        // inclusive prefix scan of sorted p
        for (int i = tid; i < GCAP; i += NT)
            sa[i] = __uint_as_float((unsigned)(gkeys[i] >> 32));
        __syncthreads();
        float* ssrc = sa; float* sdst = sb;
        for (int d = 1; d < GCAP; d <<= 1) {
            for (int i = tid; i < GCAP; i += NT)
                sdst[i] = ssrc[i] + ((i >= d) ? ssrc[i - d] : 0.0f);
            __syncthreads();
            float* tm = ssrc; ssrc = sdst; sdst = tm;
        }
        const float A_p = sh_A / sh_Zq;   // mass above the gathered set, in p units
        for (int i = tid; i < GCAP; i += NT) {
            if (i < ng) {
                float excl = (i == 0) ? A_p : (A_p + ssrc[i - 1]);
                if (excl <= topp) atomicMax(&sh_kstar, i + 1);
            }
        }
        __syncthreads();
        const int kst = sh_kstar;
        unsigned long long gb = 0ull;
        for (int i = tid; i < kst; i += NT) {
            unsigned long long key = gkeys[i];
            unsigned int idx = 0xFFFFFFFFu - (unsigned)(key & 0xFFFFFFFFull);
            float p = __uint_as_float((unsigned)(key >> 32));
            float u = urow[idx];
            float noise = fmaxf(-__logf(u), 1e-10f);
            float r = __fdividef(p, noise);
            unsigned long long k2 = ((unsigned long long)__float_as_uint(r) << 32)
                                  | (unsigned long long)(0xFFFFFFFFu - idx);
            if (k2 > gb) gb = k2;
        }
        atomicMax(&sh_best, gb);
        __syncthreads();
    }
    if (tid == 0) {
        unsigned long long kk = sh_best;
        out[row] = (int)(0xFFFFFFFFu - (unsigned)(kk & 0xFFFFFFFFull));
    }
}

extern "C" void kernel_launch(void* const* d_in, const int* in_sizes, int n_in,
                              void* d_out, int out_size, void* d_ws, size_t ws_size,
                              hipStream_t stream) {
    const float* logits = (const float*)d_in[0];
    const float* temps  = (const float*)d_in[1];
    const float* topps  = (const float*)d_in[2];
    const float* unoise = (const float*)d_in[3];
    int* out = (int*)d_out;
    hipLaunchKernelGGL(sampler_kernel, dim3(NROW), dim3(NT), 0, stream,
                       logits, temps, topps, unoise, out);
}